// Round 5
// baseline (599.609 us; speedup 1.0000x reference)
//
#include <hip/hip_runtime.h>
#include <hip/hip_bf16.h>
#include <math.h>

#define NNODES 50000
#define NEDGES 800000
#define DIM 256
#define HID_DIM 512

typedef short bf16x8 __attribute__((ext_vector_type(8)));
typedef float f32x4 __attribute__((ext_vector_type(4)));

__device__ __forceinline__ float bf2f(unsigned short u) {
    return __uint_as_float(((unsigned)u) << 16);
}
__device__ __forceinline__ unsigned short f2bf_u16(float v) {
    __hip_bfloat16 h = __float2bfloat16(v);
    return __builtin_bit_cast(unsigned short, h);
}
__device__ __forceinline__ void unpack8(uint4 v, float* f) {
    f[0] = __uint_as_float(v.x << 16); f[1] = __uint_as_float(v.x & 0xffff0000u);
    f[2] = __uint_as_float(v.y << 16); f[3] = __uint_as_float(v.y & 0xffff0000u);
    f[4] = __uint_as_float(v.z << 16); f[5] = __uint_as_float(v.z & 0xffff0000u);
    f[6] = __uint_as_float(v.w << 16); f[7] = __uint_as_float(v.w & 0xffff0000u);
}
__device__ __forceinline__ unsigned pk2(float a, float b) {
    return (unsigned)f2bf_u16(a) | ((unsigned)f2bf_u16(b) << 16);
}
__device__ __forceinline__ uint4 pack8(const float* f) {
    return make_uint4(pk2(f[0],f[1]), pk2(f[2],f[3]), pk2(f[4],f[5]), pk2(f[6],f[7]));
}

// ---------------------------------------------------------------------------
// bf16 MFMA GEMM, 64x256 tile, 4 waves (each 64x64), DIRECT-GLOBAL fragments.
// Both A[M][K] and BT[Nc][K] are K-major, and the 16x16x32 MFMA A/B fragment
// is 8 K-contiguous elems per lane (row=l16, kchunk=quad*8) -- so fragments
// load straight from global as 16B/lane vector loads. No LDS staging, no
// barriers in the main loop (R4 lesson: these 4-K-step GEMMs are latency-
// bound; barrier drains + cold GLD dominated the staged version). B panels
// are L2-resident (<=384KB), so lost cross-wave reuse costs only L2 BW.
// MODE 0: C=bf16(A@B^T + bias)
// MODE 1: C=bf16(gelu(A@B^T + bias))
// MODE 2: C=bf16(LN(resid_f32 + A@B^T + bias))   (Nc == 256)
// MODE 3: C=f32 (LN(resid_bf16 + A@B^T + bias))  (Nc == 256)
// ---------------------------------------------------------------------------
template <int MODE>
__global__ __launch_bounds__(256) void gemm_bf16_kernel(
    const __hip_bfloat16* __restrict__ A,    // [M][K]
    const __hip_bfloat16* __restrict__ BT,   // [Nc][K]
    const float* __restrict__ bias,          // [Nc] or null
    const void* __restrict__ resid,          // [M][256] f32 (MODE2) / bf16 (MODE3)
    const float* __restrict__ gam, const float* __restrict__ bet,
    __hip_bfloat16* __restrict__ Ch,         // bf16 out (MODE 0/1/2)
    float* __restrict__ Cf,                  // f32 out (MODE 3)
    int M, int K, int Nc)
{
    __shared__ __align__(16) char ldsbuf[35840];
    short* Cs = (short*)ldsbuf;               // [64][264] bf16, 33792 B (epilogue)
    float* red = (float*)(ldsbuf + 33792);    // [2][64][4] stats, 2 KB (epilogue)

    const int nTilesN = Nc >> 8;
    const int bm = blockIdx.x / nTilesN;
    const int bn = blockIdx.x - bm * nTilesN;
    const int m0 = bm << 6, n0 = bn << 8;
    const int t = threadIdx.x;
    const int wave = t >> 6, lane = t & 63;
    const int quad = lane >> 4, l16 = lane & 15;
    const int wn = wave << 6;

    f32x4 acc[4][4] = {};

    // per-lane element offsets (32-bit: max index 50000*512 < 2^25)
    unsigned aoff[4], boff[4];
    #pragma unroll
    for (int i = 0; i < 4; ++i) {
        int rm = m0 + i * 16 + l16;
        if (rm >= M) rm = M - 1;
        aoff[i] = (unsigned)rm * K + quad * 8;
    }
    #pragma unroll
    for (int j = 0; j < 4; ++j)
        boff[j] = (unsigned)(n0 + wn + j * 16 + l16) * K + quad * 8;

    #pragma unroll 2
    for (int k0 = 0; k0 < K; k0 += 32) {
        bf16x8 af[4], bfv[4];
        #pragma unroll
        for (int i = 0; i < 4; ++i)
            af[i] = *(const bf16x8*)(A + aoff[i] + k0);
        #pragma unroll
        for (int j = 0; j < 4; ++j)
            bfv[j] = *(const bf16x8*)(BT + boff[j] + k0);
        #pragma unroll
        for (int i = 0; i < 4; ++i)
            #pragma unroll
            for (int j = 0; j < 4; ++j)
                acc[i][j] = __builtin_amdgcn_mfma_f32_16x16x32_bf16(af[i], bfv[j], acc[i][j], 0, 0, 0);
    }

    // C/D layout: col = wn + j*16 + l16, row = i*16 + quad*4 + r
    float bv[4];
    #pragma unroll
    for (int j = 0; j < 4; ++j)
        bv[j] = bias ? bias[n0 + wn + j * 16 + l16] : 0.f;

    if constexpr (MODE <= 1) {
        #pragma unroll
        for (int i = 0; i < 4; ++i)
            #pragma unroll
            for (int j = 0; j < 4; ++j) {
                int col = wn + j * 16 + l16;
                #pragma unroll
                for (int r = 0; r < 4; ++r) {
                    int row = i * 16 + quad * 4 + r;
                    float v = acc[i][j][r] + bv[j];
                    if (MODE == 1) v = 0.5f * v * (1.f + erff(v * 0.70710678118654752f));
                    Cs[row * 264 + col] = (short)f2bf_u16(v);
                }
            }
        __syncthreads();
        #pragma unroll
        for (int it = 0; it < 8; ++it) {
            int ci = it * 256 + t;
            int row = ci >> 5, ck = ci & 31;
            int gm = m0 + row;
            if (gm < M) {
                uint4 v = *(const uint4*)(&Cs[row * 264 + ck * 8]);
                *(uint4*)(&Ch[(size_t)gm * Nc + n0 + ck * 8]) = v;
            }
        }
    } else {
        // ---- fp32 LN epilogue ----
        // bias + residual into fp32 acc (per-lane gather; 64B-contiguous per quad)
        #pragma unroll
        for (int i = 0; i < 4; ++i)
            #pragma unroll
            for (int r = 0; r < 4; ++r) {
                int rowg = m0 + i * 16 + quad * 4 + r;
                int rc = rowg < M ? rowg : M - 1;
                #pragma unroll
                for (int j = 0; j < 4; ++j) {
                    int col = wn + j * 16 + l16;
                    float rv;
                    if constexpr (MODE == 2)
                        rv = ((const float*)resid)[(size_t)rc * 256 + col];
                    else
                        rv = bf2f(((const unsigned short*)resid)[(size_t)rc * 256 + col]);
                    acc[i][j][r] += bv[j] + rv;
                }
            }
        // per-row sums: 4 cols/lane -> reduce over 16 l16-lanes -> LDS cross-wave
        #pragma unroll
        for (int i = 0; i < 4; ++i)
            #pragma unroll
            for (int r = 0; r < 4; ++r) {
                float ss = (acc[i][0][r] + acc[i][1][r]) + (acc[i][2][r] + acc[i][3][r]);
                float qq = (acc[i][0][r]*acc[i][0][r] + acc[i][1][r]*acc[i][1][r])
                         + (acc[i][2][r]*acc[i][2][r] + acc[i][3][r]*acc[i][3][r]);
                ss += __shfl_xor(ss, 1); ss += __shfl_xor(ss, 2);
                ss += __shfl_xor(ss, 4); ss += __shfl_xor(ss, 8);
                qq += __shfl_xor(qq, 1); qq += __shfl_xor(qq, 2);
                qq += __shfl_xor(qq, 4); qq += __shfl_xor(qq, 8);
                if (l16 == 0) {
                    int row = i * 16 + quad * 4 + r;
                    red[row * 4 + wave]       = ss;
                    red[256 + row * 4 + wave] = qq;
                }
            }
        __syncthreads();
        float mean_[4][4], inv_[4][4];
        #pragma unroll
        for (int i = 0; i < 4; ++i)
            #pragma unroll
            for (int r = 0; r < 4; ++r) {
                int row = i * 16 + quad * 4 + r;
                float4 sv = *(const float4*)&red[row * 4];
                float4 qv = *(const float4*)&red[256 + row * 4];
                float s  = (sv.x + sv.y) + (sv.z + sv.w);
                float q  = (qv.x + qv.y) + (qv.z + qv.w);
                float mean = s * (1.f / 256.f);
                float var  = q * (1.f / 256.f) - mean * mean;
                mean_[i][r] = mean;
                inv_[i][r]  = rsqrtf(var + 1e-5f);
            }
        float gv[4], btv[4];
        #pragma unroll
        for (int j = 0; j < 4; ++j) {
            int col = wn + j * 16 + l16;
            gv[j] = gam[col]; btv[j] = bet[col];
        }
        if constexpr (MODE == 2) {
            #pragma unroll
            for (int i = 0; i < 4; ++i)
                #pragma unroll
                for (int j = 0; j < 4; ++j) {
                    int col = wn + j * 16 + l16;
                    #pragma unroll
                    for (int r = 0; r < 4; ++r) {
                        int row = i * 16 + quad * 4 + r;
                        float v = (acc[i][j][r] - mean_[i][r]) * inv_[i][r] * gv[j] + btv[j];
                        Cs[row * 264 + col] = (short)f2bf_u16(v);
                    }
                }
            __syncthreads();
            #pragma unroll
            for (int it = 0; it < 8; ++it) {
                int ci = it * 256 + t;
                int row = ci >> 5, ck = ci & 31;
                int gm = m0 + row;
                if (gm < M) {
                    uint4 v = *(const uint4*)(&Cs[row * 264 + ck * 8]);
                    *(uint4*)(&Ch[(size_t)gm * 256 + ck * 8]) = v;
                }
            }
        } else {
            #pragma unroll
            for (int i = 0; i < 4; ++i)
                #pragma unroll
                for (int r = 0; r < 4; ++r) {
                    int rowg = m0 + i * 16 + quad * 4 + r;
                    if (rowg < M) {
                        #pragma unroll
                        for (int j = 0; j < 4; ++j) {
                            int col = wn + j * 16 + l16;
                            float v = (acc[i][j][r] - mean_[i][r]) * inv_[i][r] * gv[j] + btv[j];
                            Cf[(size_t)rowg * 256 + col] = v;
                        }
                    }
                }
        }
    }
}

// ---------------------------------------------------------------------------
// fp32 -> bf16 (4 elems/thread)
// ---------------------------------------------------------------------------
__global__ void conv_bf16_kernel(const float* __restrict__ in,
                                 __hip_bfloat16* __restrict__ out, int n4)
{
    int i = blockIdx.x * 256 + threadIdx.x;
    if (i < n4) {
        float4 v = ((const float4*)in)[i];
        float f[4] = {v.x, v.y, v.z, v.w};
        uint2 o = make_uint2(pk2(f[0], f[1]), pk2(f[2], f[3]));
        ((uint2*)out)[i] = o;
    }
}

// ---------------------------------------------------------------------------
// Weight prep: W[K][N] fp32 -> WT[N][K] bf16, LDS-tiled 64x64
// ---------------------------------------------------------------------------
__global__ __launch_bounds__(256) void prep_w_kernel(
    const float* __restrict__ Wq, const float* __restrict__ Wk,
    const float* __restrict__ Wv, const float* __restrict__ Wo,
    const float* __restrict__ f1, const float* __restrict__ f2,
    unsigned short* __restrict__ WqkvT, unsigned short* __restrict__ WoT,
    unsigned short* __restrict__ f1T, unsigned short* __restrict__ f2T)
{
    __shared__ unsigned short Ts[64 * 72];
    int b = blockIdx.x, t = threadIdx.x;
    const float* S; unsigned short* D; int K, N, tile;
    if (b < 64) {
        int m = b >> 4; tile = b & 15; K = 256; N = 256;
        S = (m == 0) ? Wq : (m == 1) ? Wk : (m == 2) ? Wv : Wo;
        D = (m == 3) ? WoT : WqkvT + m * 65536;
    } else if (b < 96) { tile = b - 64; S = f1; D = f1T; K = 256; N = 512; }
    else               { tile = b - 96; S = f2; D = f2T; K = 512; N = 256; }
    int tilesN = N >> 6;
    int k0 = (tile / tilesN) << 6, n0 = (tile % tilesN) << 6;
    #pragma unroll
    for (int it = 0; it < 16; ++it) {
        int idx = it * 256 + t;
        int r = idx >> 6, c = idx & 63;
        Ts[r * 72 + c] = f2bf_u16(S[(size_t)(k0 + r) * N + n0 + c]);
    }
    __syncthreads();
    #pragma unroll
    for (int it = 0; it < 16; ++it) {
        int idx = it * 256 + t;
        int r = idx >> 6, c = idx & 63;
        D[(size_t)(n0 + r) * K + k0 + c] = Ts[c * 72 + r];
    }
}

// ---------------------------------------------------------------------------
// CSR build
// ---------------------------------------------------------------------------
__global__ void hist_kernel(const int* __restrict__ dst, int* __restrict__ counts, int E)
{
    int e = blockIdx.x * blockDim.x + threadIdx.x;
    if (e < E) atomicAdd(&counts[dst[e]], 1);
}

__global__ void scan1_kernel(const int* __restrict__ counts, int* __restrict__ starts,
                             int* __restrict__ bsums, int N)
{
    __shared__ int tmp[256];
    int t = threadIdx.x;
    int i = blockIdx.x * 256 + t;
    int v = (i < N) ? counts[i] : 0;
    tmp[t] = v;
    __syncthreads();
    for (int off = 1; off < 256; off <<= 1) {
        int add = (t >= off) ? tmp[t - off] : 0;
        __syncthreads();
        tmp[t] += add;
        __syncthreads();
    }
    if (i < N) starts[i] = tmp[t] - v;
    if (t == 255) bsums[blockIdx.x] = tmp[255];
}

__global__ void scan2_kernel(const int* __restrict__ bsums, int* __restrict__ bexc, int NB)
{
    __shared__ int tmp[256];
    int t = threadIdx.x;
    int v = (t < NB) ? bsums[t] : 0;
    tmp[t] = v;
    __syncthreads();
    for (int off = 1; off < 256; off <<= 1) {
        int add = (t >= off) ? tmp[t - off] : 0;
        __syncthreads();
        tmp[t] += add;
        __syncthreads();
    }
    bexc[t] = tmp[t] - v;
}

__global__ void scan3_kernel(int* __restrict__ starts, const int* __restrict__ bexc,
                             const int* __restrict__ counts, int* __restrict__ cursor, int N)
{
    int t = threadIdx.x;
    int i = blockIdx.x * 256 + t;
    if (i < N) {
        int val = starts[i] + bexc[blockIdx.x];
        starts[i] = val;
        cursor[i] = val;
        if (i == N - 1) starts[N] = val + counts[i];
    }
}

__global__ void scatter_kernel(const int* __restrict__ src, const int* __restrict__ dst,
                               int* __restrict__ cursor, int* __restrict__ csr_src, int E)
{
    int e = blockIdx.x * blockDim.x + threadIdx.x;
    if (e < E) {
        int d = dst[e];
        int slot = atomicAdd(&cursor[d], 1);
        csr_src[slot] = src[e];
    }
}

// ---------------------------------------------------------------------------
// Attention, bf16 QKV packed [M][768]. One wave/node; lane = (edge-slot, 8ch).
// One uint4 load serves 2 edges (16B/lane). No max-subtract (scores bounded;
// shift cancels exactly). 2 pair-slots in flight (4 edges/iter).
// R0 configuration: 40 VGPR / ~17 waves/CU. R1-R3 showed waves x depth is
// invariant (~70 in-flight gathers/CU -> 112us); walled at ~3.7 TB/s
// scattered-gather service rate.
// ---------------------------------------------------------------------------
__global__ __launch_bounds__(256) void attn_kernel(
    const __hip_bfloat16* __restrict__ QKV,
    const int* __restrict__ starts, const int* __restrict__ csr_src,
    __hip_bfloat16* __restrict__ out)   // [M][256]
{
    const int n = blockIdx.x * 4 + (threadIdx.x >> 6);
    const int lane = threadIdx.x & 63;
    const int half = lane >> 5;          // which edge of the pair
    const int c = (lane & 31) << 3;      // 8-channel base
    const size_t qb = (size_t)n * 768;
    uint4 qv = *(const uint4*)(QKV + qb + c);
    float q[8]; unpack8(qv, q);
    const int beg = starts[n], end = starts[n + 1];
    const float SC = 0.17677669529663688f;   // 32^-0.5

    float l0 = 0.f, l1 = 0.f;
    float a0[8] = {0,0,0,0,0,0,0,0};
    float a1[8] = {0,0,0,0,0,0,0,0};
    for (int e = beg; e < end; e += 4) {
        int e0 = e + half, e1 = e + 2 + half;
        int s0 = csr_src[min(e0, end - 1)];
        int s1 = csr_src[min(e1, end - 1)];
        float m0 = (e0 < end) ? 1.f : 0.f;
        float m1 = (e1 < end) ? 1.f : 0.f;
        const __hip_bfloat16* p0 = QKV + (size_t)s0 * 768 + 256 + c;
        const __hip_bfloat16* p1 = QKV + (size_t)s1 * 768 + 256 + c;
        uint4 k0 = *(const uint4*)p0;
        uint4 k1 = *(const uint4*)p1;
        uint4 v0 = *(const uint4*)(p0 + 256);
        uint4 v1 = *(const uint4*)(p1 + 256);
        float kk[8], vv[8];
        unpack8(k0, kk);
        float d0 = q[0]*kk[0] + q[1]*kk[1] + q[2]*kk[2] + q[3]*kk[3]
                 + q[4]*kk[4] + q[5]*kk[5] + q[6]*kk[6] + q[7]*kk[7];
        unpack8(k1, kk);
        float d1 = q[0]*kk[0] + q[1]*kk[1] + q[2]*kk[2] + q[3]*kk[3]
                 + q[4]*kk[4] + q[5]*kk[5] + q[6]*kk[6] + q[7]*kk[7];
        d0 += __shfl_xor(d0, 1); d0 += __shfl_xor(d0, 2);
        d1 += __shfl_xor(d1, 1); d1 += __shfl_xor(d1, 2);
        float p0s = __expf(d0 * SC) * m0;
        float p1s = __expf(d1 * SC) * m1;
        l0 += p0s; l1 += p1s;
        unpack8(v0, vv);
        #pragma unroll
        for (int k = 0; k < 8; ++k) a0[k] += p0s * vv[k];
        unpack8(v1, vv);
        #pragma unroll
        for (int k = 0; k < 8; ++k) a1[k] += p1s * vv[k];
    }
    float l = l0 + l1;
    l += __shfl_xor(l, 32);
    float o[8];
    #pragma unroll
    for (int k = 0; k < 8; ++k) {
        float v = a0[k] + a1[k];
        v += __shfl_xor(v, 32);
        o[k] = v;
    }
    float inv = 1.f / (l + 1e-8f);
    #pragma unroll
    for (int k = 0; k < 8; ++k) o[k] *= inv;
    if (half == 0)
        *(uint4*)(out + (size_t)n * DIM + c) = pack8(o);
}

// ---------------------------------------------------------------------------
extern "C" void kernel_launch(void* const* d_in, const int* in_sizes, int n_in,
                              void* d_out, int out_size, void* d_ws, size_t ws_size,
                              hipStream_t stream)
{
    const float* x     = (const float*)d_in[0];
    const int*   edge  = (const int*)d_in[1];
    const float* Wq    = (const float*)d_in[3];
    const float* Wk    = (const float*)d_in[4];
    const float* Wv    = (const float*)d_in[5];
    const float* Wo_w  = (const float*)d_in[6];
    const float* Wo_b  = (const float*)d_in[7];
    const float* ln1_g = (const float*)d_in[8];
    const float* ln1_b = (const float*)d_in[9];
    const float* ln2_g = (const float*)d_in[10];
    const float* ln2_b = (const float*)d_in[11];
    const float* fw1   = (const float*)d_in[12];
    const float* fb1   = (const float*)d_in[13];
    const float* fw2   = (const float*)d_in[14];
    const float* fb2   = (const float*)d_in[15];
    const int* srcA = edge;
    const int* dstA = edge + NEDGES;

    char* p = (char*)d_ws;
    __hip_bfloat16* QKVh = (__hip_bfloat16*)p;  p += (size_t)NNODES * 768 * 2;
    __hip_bfloat16* AOh  = (__hip_bfloat16*)p;  p += (size_t)NNODES * DIM * 2;
    __hip_bfloat16* O1h  = (__hip_bfloat16*)p;  p += (size_t)NNODES * DIM * 2;
    __hip_bfloat16* HIDh = (__hip_bfloat16*)p;  p += (size_t)NNODES * HID_DIM * 2;
    __hip_bfloat16* xh   = (__hip_bfloat16*)p;  p += (size_t)NNODES * DIM * 2;
    unsigned short* WqkvT = (unsigned short*)p; p += (size_t)768 * 256 * 2;
    unsigned short* WoT   = (unsigned short*)p; p += (size_t)256 * 256 * 2;
    unsigned short* f1T   = (unsigned short*)p; p += (size_t)512 * 256 * 2;
    unsigned short* f2T   = (unsigned short*)p; p += (size_t)256 * 512 * 2;
    int* counts = (int*)p;  p += sizeof(int) * NNODES;
    int* starts = (int*)p;  p += sizeof(int) * (NNODES + 1);
    int* bsums  = (int*)p;  p += sizeof(int) * 256;
    int* bexc   = (int*)p;  p += sizeof(int) * 256;
    int* cursor = (int*)p;  p += sizeof(int) * NNODES;
    int* csr    = (int*)p;  p += sizeof(int) * NEDGES;

    const int NB = (NNODES + 255) / 256;
    const int mT = (NNODES + 63) / 64;        // 782 M-tiles
    dim3 blk(256);

    // conversions
    conv_bf16_kernel<<<(NNODES * DIM / 4 + 255) / 256, blk, 0, stream>>>(x, xh, NNODES * DIM / 4);
    prep_w_kernel<<<128, blk, 0, stream>>>(Wq, Wk, Wv, Wo_w, fw1, fw2, WqkvT, WoT, f1T, f2T);

    // CSR by dst
    hipMemsetAsync(counts, 0, sizeof(int) * NNODES, stream);
    hist_kernel<<<(NEDGES + 255) / 256, blk, 0, stream>>>(dstA, counts, NEDGES);
    scan1_kernel<<<NB, blk, 0, stream>>>(counts, starts, bsums, NNODES);
    scan2_kernel<<<1, blk, 0, stream>>>(bsums, bexc, NB);
    scan3_kernel<<<NB, blk, 0, stream>>>(starts, bexc, counts, cursor, NNODES);
    scatter_kernel<<<(NEDGES + 255) / 256, blk, 0, stream>>>(srcA, dstA, cursor, csr, NEDGES);

    // fused QKV projection: [M,256] @ [256,768]
    gemm_bf16_kernel<0><<<mT * 3, blk, 0, stream>>>(
        xh, (const __hip_bfloat16*)WqkvT, nullptr, nullptr, nullptr, nullptr,
        QKVh, nullptr, NNODES, 256, 768);

    // segmented attention
    attn_kernel<<<NNODES / 4, blk, 0, stream>>>(QKVh, starts, csr, AOh);

    // output projection + residual(x) + LN1 -> O1h (bf16)
    gemm_bf16_kernel<2><<<mT, blk, 0, stream>>>(
        AOh, (const __hip_bfloat16*)WoT, Wo_b, x, ln1_g, ln1_b,
        O1h, nullptr, NNODES, 256, 256);

    // FFN1 + GELU -> HIDh
    gemm_bf16_kernel<1><<<mT * 2, blk, 0, stream>>>(
        O1h, (const __hip_bfloat16*)f1T, fb1, nullptr, nullptr, nullptr,
        HIDh, nullptr, NNODES, 256, 512);

    // FFN2 + residual(O1h) + LN2 -> d_out (fp32)
    gemm_bf16_kernel<3><<<mT, blk, 0, stream>>>(
        HIDh, (const __hip_bfloat16*)f2T, fb2, O1h, ln2_g, ln2_b,
        nullptr, (float*)d_out, NNODES, 512, 256);
}

// Round 6
// 578.279 us; speedup vs baseline: 1.0369x; 1.0369x over previous
//
#include <hip/hip_runtime.h>
#include <hip/hip_bf16.h>
#include <math.h>

#define NNODES 50000
#define NEDGES 800000
#define DIM 256
#define HID_DIM 512

typedef short bf16x8 __attribute__((ext_vector_type(8)));
typedef float f32x4 __attribute__((ext_vector_type(4)));

__device__ __forceinline__ float bf2f(unsigned short u) {
    return __uint_as_float(((unsigned)u) << 16);
}
__device__ __forceinline__ unsigned short f2bf_u16(float v) {
    __hip_bfloat16 h = __float2bfloat16(v);
    return __builtin_bit_cast(unsigned short, h);
}
__device__ __forceinline__ void unpack8(uint4 v, float* f) {
    f[0] = __uint_as_float(v.x << 16); f[1] = __uint_as_float(v.x & 0xffff0000u);
    f[2] = __uint_as_float(v.y << 16); f[3] = __uint_as_float(v.y & 0xffff0000u);
    f[4] = __uint_as_float(v.z << 16); f[5] = __uint_as_float(v.z & 0xffff0000u);
    f[6] = __uint_as_float(v.w << 16); f[7] = __uint_as_float(v.w & 0xffff0000u);
}
__device__ __forceinline__ unsigned pk2(float a, float b) {
    return (unsigned)f2bf_u16(a) | ((unsigned)f2bf_u16(b) << 16);
}
__device__ __forceinline__ uint4 pack8(const float* f) {
    return make_uint4(pk2(f[0],f[1]), pk2(f[2],f[3]), pk2(f[4],f[5]), pk2(f[6],f[7]));
}

// async global->LDS, 16B per lane; LDS dest = wave-uniform base + lane*16
#define GLD(g, l) __builtin_amdgcn_global_load_lds( \
    (const __attribute__((address_space(1))) unsigned int*)(g), \
    (__attribute__((address_space(3))) unsigned int*)(l), 16, 0, 0)

// ---------------------------------------------------------------------------
// PERSISTENT-B GEMM (modes 0/1, K=256). Each block owns a 128-col N-slice:
// stages B[128][256] into 64KB LDS ONCE (XOR-swizzled kchunk: kc ^= row&7,
// m214 recipe for b128 reads at 512B row stride), then grid-strides over
// 64-row M-tiles with ZERO barriers / ZERO re-staging. A fragments load
// direct-from-global (16B/lane K-contiguous; validated R5). MFMA operands
// SWAPPED -- mfma(bfv, af, acc) -- so the output mapping transposes: lane
// l16 = M-row, quad*4+r = N-col => 4 consecutive cols/lane => plain 8B
// stores, no LDS transpose, no epilogue barrier. Fragment layouts of the
// A and B operands are identical (row=l16, kchunk=quad*8), so swapped
// operands need no load changes. LDS 64KB -> 2 blocks/CU.
// MODE 0: C=bf16(A@B^T + bias); MODE 1: C=bf16(gelu(A@B^T + bias)).
// ---------------------------------------------------------------------------
template <int MODE>
__global__ __launch_bounds__(256) void gemm_persist_kernel(
    const __hip_bfloat16* __restrict__ A,    // [M][256]
    const __hip_bfloat16* __restrict__ BT,   // [Nc][256]
    const float* __restrict__ bias,          // [Nc] or null
    __hip_bfloat16* __restrict__ Ch,         // [M][Nc] bf16 out
    int M, int Nc, int nsl, int mstride)
{
    constexpr int K = 256;
    constexpr int CH = K / 8;                 // 32 16B-chunks per row
    __shared__ short Bs[128 * K];             // 64 KB exactly

    const int slice = blockIdx.x % nsl;
    const int chunk = blockIdx.x / nsl;
    const int n0 = slice << 7;
    const int t = threadIdx.x;
    const int lane = t & 63;
    const int quad = lane >> 4, l16 = lane & 15;
    const int wn2 = (t >> 6) << 5;            // 32-col sub-slice per wave

    // ---- stage B slice once (write-side XOR swizzle) ----
    #pragma unroll
    for (int it = 0; it < 16; ++it) {
        int idx = it * 256 + t;
        int row = idx >> 5, c = idx & (CH - 1);
        uint4 v = *(const uint4*)(BT + (size_t)(n0 + row) * K + c * 8);
        *(uint4*)(&Bs[row * K + ((c ^ (row & 7)) << 3)]) = v;
    }
    __syncthreads();

    // per-lane bias for the 2 j-frags x 4 consecutive cols
    float bvv[2][4];
    #pragma unroll
    for (int j = 0; j < 2; ++j)
        #pragma unroll
        for (int r = 0; r < 4; ++r)
            bvv[j][r] = bias ? bias[n0 + wn2 + j * 16 + quad * 4 + r] : 0.f;

    // precompute swizzled B byte offsets for this lane's 2 rows x 8 kchunks
    const int NTM = (M + 63) >> 6;
    for (int mt = chunk; mt < NTM; mt += mstride) {
        const int m0 = mt << 6;
        const __hip_bfloat16* abase[4];
        #pragma unroll
        for (int i = 0; i < 4; ++i) {
            int rm = m0 + i * 16 + l16;
            if (rm >= M) rm = M - 1;
            abase[i] = A + (size_t)rm * K + quad * 8;
        }
        f32x4 acc[4][2] = {};
        #pragma unroll
        for (int ks = 0; ks < 8; ++ks) {
            bf16x8 af[4], bfv[2];
            #pragma unroll
            for (int i = 0; i < 4; ++i)
                af[i] = *(const bf16x8*)(abase[i] + ks * 32);
            #pragma unroll
            for (int j = 0; j < 2; ++j) {
                int row = wn2 + j * 16 + l16;
                int kc = ks * 4 + quad;
                bfv[j] = *(const bf16x8*)(&Bs[row * K + ((kc ^ (row & 7)) << 3)]);
            }
            #pragma unroll
            for (int i = 0; i < 4; ++i)
                #pragma unroll
                for (int j = 0; j < 2; ++j)
                    acc[i][j] = __builtin_amdgcn_mfma_f32_16x16x32_bf16(bfv[j], af[i], acc[i][j], 0, 0, 0);
        }
        // store: lane l16 = M-row (m0+i*16+l16); cols n0+wn2+j*16+quad*4+r
        #pragma unroll
        for (int i = 0; i < 4; ++i) {
            int m = m0 + i * 16 + l16;
            if (m < M) {
                #pragma unroll
                for (int j = 0; j < 2; ++j) {
                    float v0 = acc[i][j][0] + bvv[j][0];
                    float v1 = acc[i][j][1] + bvv[j][1];
                    float v2 = acc[i][j][2] + bvv[j][2];
                    float v3 = acc[i][j][3] + bvv[j][3];
                    if (MODE == 1) {
                        v0 = 0.5f * v0 * (1.f + erff(v0 * 0.70710678118654752f));
                        v1 = 0.5f * v1 * (1.f + erff(v1 * 0.70710678118654752f));
                        v2 = 0.5f * v2 * (1.f + erff(v2 * 0.70710678118654752f));
                        v3 = 0.5f * v3 * (1.f + erff(v3 * 0.70710678118654752f));
                    }
                    uint2 o = make_uint2(pk2(v0, v1), pk2(v2, v3));
                    *(uint2*)(&Ch[(size_t)m * Nc + n0 + wn2 + j * 16 + quad * 4]) = o;
                }
            }
        }
    }
}

// ---------------------------------------------------------------------------
// bf16 MFMA GEMM, 64x256 tile, BK=64, 4 waves (each 64x64). R0-proven staged
// structure, used for the LN epilogues.
// MODE 2: C=bf16(LN(resid_f32 + A@B^T + bias))   (Nc == 256)
// MODE 3: C=f32 (LN(resid_bf16 + A@B^T + bias))  (Nc == 256)
// ---------------------------------------------------------------------------
template <int MODE>
__global__ __launch_bounds__(256) void gemm_bf16_kernel(
    const __hip_bfloat16* __restrict__ A,    // [M][K]
    const __hip_bfloat16* __restrict__ BT,   // [Nc][K]
    const float* __restrict__ bias,          // [Nc] or null
    const void* __restrict__ resid,          // [M][256] f32 (MODE2) / bf16 (MODE3)
    const float* __restrict__ gam, const float* __restrict__ bet,
    __hip_bfloat16* __restrict__ Ch,         // bf16 out (MODE 2)
    float* __restrict__ Cf,                  // f32 out (MODE 3)
    int M, int K, int Nc)
{
    __shared__ __align__(16) char ldsbuf[40960];
    short* As = (short*)ldsbuf;               // [64][64]   8 KB
    short* Bs = (short*)(ldsbuf + 8192);      // [256][64] 32 KB
    short* Cs = (short*)ldsbuf;               // [64][264] bf16, 33792 B (epilogue)
    float* red = (float*)(ldsbuf + 33792);    // [2][64][4] stats, 2 KB (epilogue)

    const int nTilesN = Nc >> 8;
    const int bm = blockIdx.x / nTilesN;
    const int bn = blockIdx.x - bm * nTilesN;
    const int m0 = bm << 6, n0 = bn << 8;
    const int t = threadIdx.x;
    const int wave = t >> 6, lane = t & 63;
    const int quad = lane >> 4, l16 = lane & 15;
    const int wn = wave << 6;

    f32x4 acc[4][4] = {};

    const int rr = lane >> 3, chk = lane & 7;
    const int gcol = (chk ^ rr) << 3;
    size_t aoff[2], boff[8];
    #pragma unroll
    for (int g = 0; g < 2; ++g) {
        int gm = m0 + (wave * 2 + g) * 8 + rr;
        if (gm >= M) gm = M - 1;
        aoff[g] = (size_t)gm * K + gcol;
    }
    #pragma unroll
    for (int g = 0; g < 8; ++g)
        boff[g] = (size_t)(n0 + (wave * 8 + g) * 8 + rr) * K + gcol;

    for (int k0 = 0; k0 < K; k0 += 64) {
        #pragma unroll
        for (int g = 0; g < 2; ++g)
            GLD(A + aoff[g] + k0, &As[(wave * 2 + g) * 512]);
        #pragma unroll
        for (int g = 0; g < 8; ++g)
            GLD(BT + boff[g] + k0, &Bs[(wave * 8 + g) * 512]);
        __syncthreads();
        #pragma unroll
        for (int kk = 0; kk < 2; ++kk) {
            const int cswz = quad + kk * 4;
            bf16x8 af[4], bfv[4];
            #pragma unroll
            for (int i = 0; i < 4; ++i) {
                int row = i * 16 + l16;
                af[i] = *(const bf16x8*)(&As[row * 64 + ((cswz ^ (row & 7)) << 3)]);
            }
            #pragma unroll
            for (int j = 0; j < 4; ++j) {
                int row = wn + j * 16 + l16;
                bfv[j] = *(const bf16x8*)(&Bs[row * 64 + ((cswz ^ (row & 7)) << 3)]);
            }
            #pragma unroll
            for (int i = 0; i < 4; ++i)
                #pragma unroll
                for (int j = 0; j < 4; ++j)
                    acc[i][j] = __builtin_amdgcn_mfma_f32_16x16x32_bf16(af[i], bfv[j], acc[i][j], 0, 0, 0);
        }
        __syncthreads();
    }

    // C/D layout: col = wn + j*16 + l16, row = i*16 + quad*4 + r
    float bv[4];
    #pragma unroll
    for (int j = 0; j < 4; ++j)
        bv[j] = bias ? bias[n0 + wn + j * 16 + l16] : 0.f;

    // ---- fp32 LN epilogue ----
    #pragma unroll
    for (int i = 0; i < 4; ++i)
        #pragma unroll
        for (int r = 0; r < 4; ++r) {
            int rowg = m0 + i * 16 + quad * 4 + r;
            int rc = rowg < M ? rowg : M - 1;
            #pragma unroll
            for (int j = 0; j < 4; ++j) {
                int col = wn + j * 16 + l16;
                float rv;
                if constexpr (MODE == 2)
                    rv = ((const float*)resid)[(size_t)rc * 256 + col];
                else
                    rv = bf2f(((const unsigned short*)resid)[(size_t)rc * 256 + col]);
                acc[i][j][r] += bv[j] + rv;
            }
        }
    #pragma unroll
    for (int i = 0; i < 4; ++i)
        #pragma unroll
        for (int r = 0; r < 4; ++r) {
            float ss = (acc[i][0][r] + acc[i][1][r]) + (acc[i][2][r] + acc[i][3][r]);
            float qq = (acc[i][0][r]*acc[i][0][r] + acc[i][1][r]*acc[i][1][r])
                     + (acc[i][2][r]*acc[i][2][r] + acc[i][3][r]*acc[i][3][r]);
            ss += __shfl_xor(ss, 1); ss += __shfl_xor(ss, 2);
            ss += __shfl_xor(ss, 4); ss += __shfl_xor(ss, 8);
            qq += __shfl_xor(qq, 1); qq += __shfl_xor(qq, 2);
            qq += __shfl_xor(qq, 4); qq += __shfl_xor(qq, 8);
            if (l16 == 0) {
                int row = i * 16 + quad * 4 + r;
                red[row * 4 + wave]       = ss;
                red[256 + row * 4 + wave] = qq;
            }
        }
    __syncthreads();
    float mean_[4][4], inv_[4][4];
    #pragma unroll
    for (int i = 0; i < 4; ++i)
        #pragma unroll
        for (int r = 0; r < 4; ++r) {
            int row = i * 16 + quad * 4 + r;
            float4 sv = *(const float4*)&red[row * 4];
            float4 qv = *(const float4*)&red[256 + row * 4];
            float s  = (sv.x + sv.y) + (sv.z + sv.w);
            float q  = (qv.x + qv.y) + (qv.z + qv.w);
            float mean = s * (1.f / 256.f);
            float var  = q * (1.f / 256.f) - mean * mean;
            mean_[i][r] = mean;
            inv_[i][r]  = rsqrtf(var + 1e-5f);
        }
    float gv[4], btv[4];
    #pragma unroll
    for (int j = 0; j < 4; ++j) {
        int col = wn + j * 16 + l16;
        gv[j] = gam[col]; btv[j] = bet[col];
    }
    if constexpr (MODE == 2) {
        #pragma unroll
        for (int i = 0; i < 4; ++i)
            #pragma unroll
            for (int j = 0; j < 4; ++j) {
                int col = wn + j * 16 + l16;
                #pragma unroll
                for (int r = 0; r < 4; ++r) {
                    int row = i * 16 + quad * 4 + r;
                    float v = (acc[i][j][r] - mean_[i][r]) * inv_[i][r] * gv[j] + btv[j];
                    Cs[row * 264 + col] = (short)f2bf_u16(v);
                }
            }
        __syncthreads();
        #pragma unroll
        for (int it = 0; it < 8; ++it) {
            int ci = it * 256 + t;
            int row = ci >> 5, ck = ci & 31;
            int gm = m0 + row;
            if (gm < M) {
                uint4 v = *(const uint4*)(&Cs[row * 264 + ck * 8]);
                *(uint4*)(&Ch[(size_t)gm * 256 + ck * 8]) = v;
            }
        }
    } else {
        #pragma unroll
        for (int i = 0; i < 4; ++i)
            #pragma unroll
            for (int r = 0; r < 4; ++r) {
                int rowg = m0 + i * 16 + quad * 4 + r;
                if (rowg < M) {
                    #pragma unroll
                    for (int j = 0; j < 4; ++j) {
                        int col = wn + j * 16 + l16;
                        float v = (acc[i][j][r] - mean_[i][r]) * inv_[i][r] * gv[j] + btv[j];
                        Cf[(size_t)rowg * 256 + col] = v;
                    }
                }
            }
    }
}

// ---------------------------------------------------------------------------
// fp32 -> bf16 (4 elems/thread)
// ---------------------------------------------------------------------------
__global__ void conv_bf16_kernel(const float* __restrict__ in,
                                 __hip_bfloat16* __restrict__ out, int n4)
{
    int i = blockIdx.x * 256 + threadIdx.x;
    if (i < n4) {
        float4 v = ((const float4*)in)[i];
        float f[4] = {v.x, v.y, v.z, v.w};
        uint2 o = make_uint2(pk2(f[0], f[1]), pk2(f[2], f[3]));
        ((uint2*)out)[i] = o;
    }
}

// ---------------------------------------------------------------------------
// Weight prep: W[K][N] fp32 -> WT[N][K] bf16, LDS-tiled 64x64
// ---------------------------------------------------------------------------
__global__ __launch_bounds__(256) void prep_w_kernel(
    const float* __restrict__ Wq, const float* __restrict__ Wk,
    const float* __restrict__ Wv, const float* __restrict__ Wo,
    const float* __restrict__ f1, const float* __restrict__ f2,
    unsigned short* __restrict__ WqkvT, unsigned short* __restrict__ WoT,
    unsigned short* __restrict__ f1T, unsigned short* __restrict__ f2T)
{
    __shared__ unsigned short Ts[64 * 72];
    int b = blockIdx.x, t = threadIdx.x;
    const float* S; unsigned short* D; int K, N, tile;
    if (b < 64) {
        int m = b >> 4; tile = b & 15; K = 256; N = 256;
        S = (m == 0) ? Wq : (m == 1) ? Wk : (m == 2) ? Wv : Wo;
        D = (m == 3) ? WoT : WqkvT + m * 65536;
    } else if (b < 96) { tile = b - 64; S = f1; D = f1T; K = 256; N = 512; }
    else               { tile = b - 96; S = f2; D = f2T; K = 512; N = 256; }
    int tilesN = N >> 6;
    int k0 = (tile / tilesN) << 6, n0 = (tile % tilesN) << 6;
    #pragma unroll
    for (int it = 0; it < 16; ++it) {
        int idx = it * 256 + t;
        int r = idx >> 6, c = idx & 63;
        Ts[r * 72 + c] = f2bf_u16(S[(size_t)(k0 + r) * N + n0 + c]);
    }
    __syncthreads();
    #pragma unroll
    for (int it = 0; it < 16; ++it) {
        int idx = it * 256 + t;
        int r = idx >> 6, c = idx & 63;
        D[(size_t)(n0 + r) * K + k0 + c] = Ts[c * 72 + r];
    }
}

// ---------------------------------------------------------------------------
// CSR build
// ---------------------------------------------------------------------------
__global__ void hist_kernel(const int* __restrict__ dst, int* __restrict__ counts, int E)
{
    int e = blockIdx.x * blockDim.x + threadIdx.x;
    if (e < E) atomicAdd(&counts[dst[e]], 1);
}

__global__ void scan1_kernel(const int* __restrict__ counts, int* __restrict__ starts,
                             int* __restrict__ bsums, int N)
{
    __shared__ int tmp[256];
    int t = threadIdx.x;
    int i = blockIdx.x * 256 + t;
    int v = (i < N) ? counts[i] : 0;
    tmp[t] = v;
    __syncthreads();
    for (int off = 1; off < 256; off <<= 1) {
        int add = (t >= off) ? tmp[t - off] : 0;
        __syncthreads();
        tmp[t] += add;
        __syncthreads();
    }
    if (i < N) starts[i] = tmp[t] - v;
    if (t == 255) bsums[blockIdx.x] = tmp[255];
}

__global__ void scan2_kernel(const int* __restrict__ bsums, int* __restrict__ bexc, int NB)
{
    __shared__ int tmp[256];
    int t = threadIdx.x;
    int v = (t < NB) ? bsums[t] : 0;
    tmp[t] = v;
    __syncthreads();
    for (int off = 1; off < 256; off <<= 1) {
        int add = (t >= off) ? tmp[t - off] : 0;
        __syncthreads();
        tmp[t] += add;
        __syncthreads();
    }
    bexc[t] = tmp[t] - v;
}

__global__ void scan3_kernel(int* __restrict__ starts, const int* __restrict__ bexc,
                             const int* __restrict__ counts, int* __restrict__ cursor, int N)
{
    int t = threadIdx.x;
    int i = blockIdx.x * 256 + t;
    if (i < N) {
        int val = starts[i] + bexc[blockIdx.x];
        starts[i] = val;
        cursor[i] = val;
        if (i == N - 1) starts[N] = val + counts[i];
    }
}

__global__ void scatter_kernel(const int* __restrict__ src, const int* __restrict__ dst,
                               int* __restrict__ cursor, int* __restrict__ csr_src, int E)
{
    int e = blockIdx.x * blockDim.x + threadIdx.x;
    if (e < E) {
        int d = dst[e];
        int slot = atomicAdd(&cursor[d], 1);
        csr_src[slot] = src[e];
    }
}

// ---------------------------------------------------------------------------
// Attention, bf16 QKV packed [M][768]. One wave/node; lane = (edge-slot, 8ch).
// One uint4 load serves 2 edges (16B/lane). No max-subtract (scores bounded;
// shift cancels exactly). 2 pair-slots in flight (4 edges/iter).
// R0 configuration: 40 VGPR / ~17 waves/CU. R1-R3 showed waves x depth is
// invariant (~70 in-flight gathers/CU -> 112us); walled at ~3.7 TB/s
// scattered-gather service rate.
// ---------------------------------------------------------------------------
__global__ __launch_bounds__(256) void attn_kernel(
    const __hip_bfloat16* __restrict__ QKV,
    const int* __restrict__ starts, const int* __restrict__ csr_src,
    __hip_bfloat16* __restrict__ out)   // [M][256]
{
    const int n = blockIdx.x * 4 + (threadIdx.x >> 6);
    const int lane = threadIdx.x & 63;
    const int half = lane >> 5;          // which edge of the pair
    const int c = (lane & 31) << 3;      // 8-channel base
    const size_t qb = (size_t)n * 768;
    uint4 qv = *(const uint4*)(QKV + qb + c);
    float q[8]; unpack8(qv, q);
    const int beg = starts[n], end = starts[n + 1];
    const float SC = 0.17677669529663688f;   // 32^-0.5

    float l0 = 0.f, l1 = 0.f;
    float a0[8] = {0,0,0,0,0,0,0,0};
    float a1[8] = {0,0,0,0,0,0,0,0};
    for (int e = beg; e < end; e += 4) {
        int e0 = e + half, e1 = e + 2 + half;
        int s0 = csr_src[min(e0, end - 1)];
        int s1 = csr_src[min(e1, end - 1)];
        float m0 = (e0 < end) ? 1.f : 0.f;
        float m1 = (e1 < end) ? 1.f : 0.f;
        const __hip_bfloat16* p0 = QKV + (size_t)s0 * 768 + 256 + c;
        const __hip_bfloat16* p1 = QKV + (size_t)s1 * 768 + 256 + c;
        uint4 k0 = *(const uint4*)p0;
        uint4 k1 = *(const uint4*)p1;
        uint4 v0 = *(const uint4*)(p0 + 256);
        uint4 v1 = *(const uint4*)(p1 + 256);
        float kk[8], vv[8];
        unpack8(k0, kk);
        float d0 = q[0]*kk[0] + q[1]*kk[1] + q[2]*kk[2] + q[3]*kk[3]
                 + q[4]*kk[4] + q[5]*kk[5] + q[6]*kk[6] + q[7]*kk[7];
        unpack8(k1, kk);
        float d1 = q[0]*kk[0] + q[1]*kk[1] + q[2]*kk[2] + q[3]*kk[3]
                 + q[4]*kk[4] + q[5]*kk[5] + q[6]*kk[6] + q[7]*kk[7];
        d0 += __shfl_xor(d0, 1); d0 += __shfl_xor(d0, 2);
        d1 += __shfl_xor(d1, 1); d1 += __shfl_xor(d1, 2);
        float p0s = __expf(d0 * SC) * m0;
        float p1s = __expf(d1 * SC) * m1;
        l0 += p0s; l1 += p1s;
        unpack8(v0, vv);
        #pragma unroll
        for (int k = 0; k < 8; ++k) a0[k] += p0s * vv[k];
        unpack8(v1, vv);
        #pragma unroll
        for (int k = 0; k < 8; ++k) a1[k] += p1s * vv[k];
    }
    float l = l0 + l1;
    l += __shfl_xor(l, 32);
    float o[8];
    #pragma unroll
    for (int k = 0; k < 8; ++k) {
        float v = a0[k] + a1[k];
        v += __shfl_xor(v, 32);
        o[k] = v;
    }
    float inv = 1.f / (l + 1e-8f);
    #pragma unroll
    for (int k = 0; k < 8; ++k) o[k] *= inv;
    if (half == 0)
        *(uint4*)(out + (size_t)n * DIM + c) = pack8(o);
}

// ---------------------------------------------------------------------------
extern "C" void kernel_launch(void* const* d_in, const int* in_sizes, int n_in,
                              void* d_out, int out_size, void* d_ws, size_t ws_size,
                              hipStream_t stream)
{
    const float* x     = (const float*)d_in[0];
    const int*   edge  = (const int*)d_in[1];
    const float* Wq    = (const float*)d_in[3];
    const float* Wk    = (const float*)d_in[4];
    const float* Wv    = (const float*)d_in[5];
    const float* Wo_w  = (const float*)d_in[6];
    const float* Wo_b  = (const float*)d_in[7];
    const float* ln1_g = (const float*)d_in[8];
    const float* ln1_b = (const float*)d_in[9];
    const float* ln2_g = (const float*)d_in[10];
    const float* ln2_b = (const float*)d_in[11];
    const float* fw1   = (const float*)d_in[12];
    const float* fb1   = (const float*)d_in[13];
    const float* fw2   = (const float*)d_in[14];
    const float* fb2   = (const float*)d_in[15];
    const int* srcA = edge;
    const int* dstA = edge + NEDGES;

    char* p = (char*)d_ws;
    __hip_bfloat16* QKVh = (__hip_bfloat16*)p;  p += (size_t)NNODES * 768 * 2;
    __hip_bfloat16* AOh  = (__hip_bfloat16*)p;  p += (size_t)NNODES * DIM * 2;
    __hip_bfloat16* O1h  = (__hip_bfloat16*)p;  p += (size_t)NNODES * DIM * 2;
    __hip_bfloat16* HIDh = (__hip_bfloat16*)p;  p += (size_t)NNODES * HID_DIM * 2;
    __hip_bfloat16* xh   = (__hip_bfloat16*)p;  p += (size_t)NNODES * DIM * 2;
    unsigned short* WqkvT = (unsigned short*)p; p += (size_t)768 * 256 * 2;
    unsigned short* WoT   = (unsigned short*)p; p += (size_t)256 * 256 * 2;
    unsigned short* f1T   = (unsigned short*)p; p += (size_t)512 * 256 * 2;
    unsigned short* f2T   = (unsigned short*)p; p += (size_t)256 * 512 * 2;
    int* counts = (int*)p;  p += sizeof(int) * NNODES;
    int* starts = (int*)p;  p += sizeof(int) * (NNODES + 1);
    int* bsums  = (int*)p;  p += sizeof(int) * 256;
    int* bexc   = (int*)p;  p += sizeof(int) * 256;
    int* cursor = (int*)p;  p += sizeof(int) * NNODES;
    int* csr    = (int*)p;  p += sizeof(int) * NEDGES;

    const int NB = (NNODES + 255) / 256;
    const int mT = (NNODES + 63) / 64;        // 782 M-tiles
    dim3 blk(256);

    // conversions
    conv_bf16_kernel<<<(NNODES * DIM / 4 + 255) / 256, blk, 0, stream>>>(x, xh, NNODES * DIM / 4);
    prep_w_kernel<<<128, blk, 0, stream>>>(Wq, Wk, Wv, Wo_w, fw1, fw2, WqkvT, WoT, f1T, f2T);

    // CSR by dst
    hipMemsetAsync(counts, 0, sizeof(int) * NNODES, stream);
    hist_kernel<<<(NEDGES + 255) / 256, blk, 0, stream>>>(dstA, counts, NEDGES);
    scan1_kernel<<<NB, blk, 0, stream>>>(counts, starts, bsums, NNODES);
    scan2_kernel<<<1, blk, 0, stream>>>(bsums, bexc, NB);
    scan3_kernel<<<NB, blk, 0, stream>>>(starts, bexc, counts, cursor, NNODES);
    scatter_kernel<<<(NEDGES + 255) / 256, blk, 0, stream>>>(srcA, dstA, cursor, csr, NEDGES);

    // fused QKV projection: [M,256] @ [256,768], persistent-B (6 slices x 85 chunks)
    gemm_persist_kernel<0><<<6 * 85, blk, 0, stream>>>(
        xh, (const __hip_bfloat16*)WqkvT, nullptr, QKVh, NNODES, 768, 6, 85);

    // segmented attention
    attn_kernel<<<NNODES / 4, blk, 0, stream>>>(QKVh, starts, csr, AOh);

    // output projection + residual(x) + LN1 -> O1h (bf16)
    gemm_bf16_kernel<2><<<mT, blk, 0, stream>>>(
        AOh, (const __hip_bfloat16*)WoT, Wo_b, x, ln1_g, ln1_b,
        O1h, nullptr, NNODES, 256, 256);

    // FFN1 + GELU -> HIDh, persistent-B (4 slices x 128 chunks)
    gemm_persist_kernel<1><<<4 * 128, blk, 0, stream>>>(
        O1h, (const __hip_bfloat16*)f1T, fb1, HIDh, NNODES, 512, 4, 128);

    // FFN2 + residual(O1h) + LN2 -> d_out (fp32)
    gemm_bf16_kernel<3><<<mT, blk, 0, stream>>>(
        HIDh, (const __hip_bfloat16*)f2T, fb2, O1h, ln2_g, ln2_b,
        nullptr, (float*)d_out, NNODES, 512, 256);
}

// Round 7
// 505.292 us; speedup vs baseline: 1.1867x; 1.1444x over previous
//
#include <hip/hip_runtime.h>
#include <hip/hip_bf16.h>
#include <math.h>

#define NNODES 50000
#define NEDGES 800000
#define DIM 256
#define HID_DIM 512

typedef short bf16x8 __attribute__((ext_vector_type(8)));
typedef float f32x4 __attribute__((ext_vector_type(4)));

__device__ __forceinline__ float bf2f(unsigned short u) {
    return __uint_as_float(((unsigned)u) << 16);
}
__device__ __forceinline__ unsigned short f2bf_u16(float v) {
    __hip_bfloat16 h = __float2bfloat16(v);
    return __builtin_bit_cast(unsigned short, h);
}
__device__ __forceinline__ void unpack8(uint4 v, float* f) {
    f[0] = __uint_as_float(v.x << 16); f[1] = __uint_as_float(v.x & 0xffff0000u);
    f[2] = __uint_as_float(v.y << 16); f[3] = __uint_as_float(v.y & 0xffff0000u);
    f[4] = __uint_as_float(v.z << 16); f[5] = __uint_as_float(v.z & 0xffff0000u);
    f[6] = __uint_as_float(v.w << 16); f[7] = __uint_as_float(v.w & 0xffff0000u);
}
__device__ __forceinline__ unsigned pk2(float a, float b) {
    return (unsigned)f2bf_u16(a) | ((unsigned)f2bf_u16(b) << 16);
}
__device__ __forceinline__ uint4 pack8(const float* f) {
    return make_uint4(pk2(f[0],f[1]), pk2(f[2],f[3]), pk2(f[4],f[5]), pk2(f[6],f[7]));
}

// async global->LDS, 16B per lane; LDS dest = wave-uniform base + lane*16
#define GLD(g, l) __builtin_amdgcn_global_load_lds( \
    (const __attribute__((address_space(1))) unsigned int*)(g), \
    (__attribute__((address_space(3))) unsigned int*)(l), 16, 0, 0)

// ---------------------------------------------------------------------------
// bf16 MFMA GEMM, 64x256 tile, BK=64, 4 waves (each 64x64). R0-proven
// structure: 40KB LDS -> 4 blocks/CU (16 waves/CU). Session evidence
// (R4 gemm128, R5 direct-global, R6 persistent-B) shows every variant that
// trades occupancy for per-wave efficiency loses 60-85us on these short
// K=256 pipelines. Per-CU per-K-step demand is balanced (LDS ~2048cy ~=
// MFMA ~2064cy), so this config sits near the co-critical point.
// KK is compile-time so the 4-8 step K-loop fully unrolls (constant-folded
// GLD addressing; no structural change).
// MODE 0: C=bf16(A@B^T + bias)
// MODE 1: C=bf16(gelu(A@B^T + bias))
// MODE 2: C=bf16(LN(resid_f32 + A@B^T + bias))   (Nc == 256)
// MODE 3: C=f32 (LN(resid_bf16 + A@B^T + bias))  (Nc == 256)
// ---------------------------------------------------------------------------
template <int MODE, int KK>
__global__ __launch_bounds__(256) void gemm_bf16_kernel(
    const __hip_bfloat16* __restrict__ A,    // [M][KK]
    const __hip_bfloat16* __restrict__ BT,   // [Nc][KK]
    const float* __restrict__ bias,          // [Nc] or null
    const void* __restrict__ resid,          // [M][256] f32 (MODE2) / bf16 (MODE3)
    const float* __restrict__ gam, const float* __restrict__ bet,
    __hip_bfloat16* __restrict__ Ch,         // bf16 out (MODE 0/1/2)
    float* __restrict__ Cf,                  // f32 out (MODE 3)
    int M, int Nc)
{
    __shared__ __align__(16) char ldsbuf[40960];
    short* As = (short*)ldsbuf;               // [64][64]   8 KB
    short* Bs = (short*)(ldsbuf + 8192);      // [256][64] 32 KB
    short* Cs = (short*)ldsbuf;               // [64][264] bf16, 33792 B (epilogue)
    float* red = (float*)(ldsbuf + 33792);    // [2][64][4] stats, 2 KB (epilogue)

    const int nTilesN = Nc >> 8;
    const int bm = blockIdx.x / nTilesN;
    const int bn = blockIdx.x - bm * nTilesN;
    const int m0 = bm << 6, n0 = bn << 8;
    const int t = threadIdx.x;
    const int wave = t >> 6, lane = t & 63;
    const int quad = lane >> 4, l16 = lane & 15;
    const int wn = wave << 6;

    f32x4 acc[4][4] = {};

    const int rr = lane >> 3, chk = lane & 7;
    const int gcol = (chk ^ rr) << 3;
    size_t aoff[2], boff[8];
    #pragma unroll
    for (int g = 0; g < 2; ++g) {
        int gm = m0 + (wave * 2 + g) * 8 + rr;
        if (gm >= M) gm = M - 1;
        aoff[g] = (size_t)gm * KK + gcol;
    }
    #pragma unroll
    for (int g = 0; g < 8; ++g)
        boff[g] = (size_t)(n0 + (wave * 8 + g) * 8 + rr) * KK + gcol;

    #pragma unroll
    for (int k0 = 0; k0 < KK; k0 += 64) {
        #pragma unroll
        for (int g = 0; g < 2; ++g)
            GLD(A + aoff[g] + k0, &As[(wave * 2 + g) * 512]);
        #pragma unroll
        for (int g = 0; g < 8; ++g)
            GLD(BT + boff[g] + k0, &Bs[(wave * 8 + g) * 512]);
        __syncthreads();
        #pragma unroll
        for (int kk = 0; kk < 2; ++kk) {
            const int cswz = quad + kk * 4;
            bf16x8 af[4], bfv[4];
            #pragma unroll
            for (int i = 0; i < 4; ++i) {
                int row = i * 16 + l16;
                af[i] = *(const bf16x8*)(&As[row * 64 + ((cswz ^ (row & 7)) << 3)]);
            }
            #pragma unroll
            for (int j = 0; j < 4; ++j) {
                int row = wn + j * 16 + l16;
                bfv[j] = *(const bf16x8*)(&Bs[row * 64 + ((cswz ^ (row & 7)) << 3)]);
            }
            #pragma unroll
            for (int i = 0; i < 4; ++i)
                #pragma unroll
                for (int j = 0; j < 4; ++j)
                    acc[i][j] = __builtin_amdgcn_mfma_f32_16x16x32_bf16(af[i], bfv[j], acc[i][j], 0, 0, 0);
        }
        __syncthreads();
    }

    // C/D layout: col = wn + j*16 + l16, row = i*16 + quad*4 + r
    float bv[4];
    #pragma unroll
    for (int j = 0; j < 4; ++j)
        bv[j] = bias ? bias[n0 + wn + j * 16 + l16] : 0.f;

    if constexpr (MODE <= 1) {
        #pragma unroll
        for (int i = 0; i < 4; ++i)
            #pragma unroll
            for (int j = 0; j < 4; ++j) {
                int col = wn + j * 16 + l16;
                #pragma unroll
                for (int r = 0; r < 4; ++r) {
                    int row = i * 16 + quad * 4 + r;
                    float v = acc[i][j][r] + bv[j];
                    if (MODE == 1) v = 0.5f * v * (1.f + erff(v * 0.70710678118654752f));
                    Cs[row * 264 + col] = (short)f2bf_u16(v);
                }
            }
        __syncthreads();
        #pragma unroll
        for (int it = 0; it < 8; ++it) {
            int ci = it * 256 + t;
            int row = ci >> 5, ck = ci & 31;
            int gm = m0 + row;
            if (gm < M) {
                uint4 v = *(const uint4*)(&Cs[row * 264 + ck * 8]);
                *(uint4*)(&Ch[(size_t)gm * Nc + n0 + ck * 8]) = v;
            }
        }
    } else {
        // ---- fp32 LN epilogue ----
        // bias + residual into fp32 acc (per-lane gather; 64B-contiguous per quad)
        #pragma unroll
        for (int i = 0; i < 4; ++i)
            #pragma unroll
            for (int r = 0; r < 4; ++r) {
                int rowg = m0 + i * 16 + quad * 4 + r;
                int rc = rowg < M ? rowg : M - 1;
                #pragma unroll
                for (int j = 0; j < 4; ++j) {
                    int col = wn + j * 16 + l16;
                    float rv;
                    if constexpr (MODE == 2)
                        rv = ((const float*)resid)[(size_t)rc * 256 + col];
                    else
                        rv = bf2f(((const unsigned short*)resid)[(size_t)rc * 256 + col]);
                    acc[i][j][r] += bv[j] + rv;
                }
            }
        // per-row sums: 4 cols/lane -> reduce over 16 l16-lanes -> LDS cross-wave
        #pragma unroll
        for (int i = 0; i < 4; ++i)
            #pragma unroll
            for (int r = 0; r < 4; ++r) {
                float ss = (acc[i][0][r] + acc[i][1][r]) + (acc[i][2][r] + acc[i][3][r]);
                float qq = (acc[i][0][r]*acc[i][0][r] + acc[i][1][r]*acc[i][1][r])
                         + (acc[i][2][r]*acc[i][2][r] + acc[i][3][r]*acc[i][3][r]);
                ss += __shfl_xor(ss, 1); ss += __shfl_xor(ss, 2);
                ss += __shfl_xor(ss, 4); ss += __shfl_xor(ss, 8);
                qq += __shfl_xor(qq, 1); qq += __shfl_xor(qq, 2);
                qq += __shfl_xor(qq, 4); qq += __shfl_xor(qq, 8);
                if (l16 == 0) {
                    int row = i * 16 + quad * 4 + r;
                    red[row * 4 + wave]       = ss;
                    red[256 + row * 4 + wave] = qq;
                }
            }
        __syncthreads();
        float mean_[4][4], inv_[4][4];
        #pragma unroll
        for (int i = 0; i < 4; ++i)
            #pragma unroll
            for (int r = 0; r < 4; ++r) {
                int row = i * 16 + quad * 4 + r;
                float4 sv = *(const float4*)&red[row * 4];
                float4 qv = *(const float4*)&red[256 + row * 4];
                float s  = (sv.x + sv.y) + (sv.z + sv.w);
                float q  = (qv.x + qv.y) + (qv.z + qv.w);
                float mean = s * (1.f / 256.f);
                float var  = q * (1.f / 256.f) - mean * mean;
                mean_[i][r] = mean;
                inv_[i][r]  = rsqrtf(var + 1e-5f);
            }
        float gv[4], btv[4];
        #pragma unroll
        for (int j = 0; j < 4; ++j) {
            int col = wn + j * 16 + l16;
            gv[j] = gam[col]; btv[j] = bet[col];
        }
        if constexpr (MODE == 2) {
            #pragma unroll
            for (int i = 0; i < 4; ++i)
                #pragma unroll
                for (int j = 0; j < 4; ++j) {
                    int col = wn + j * 16 + l16;
                    #pragma unroll
                    for (int r = 0; r < 4; ++r) {
                        int row = i * 16 + quad * 4 + r;
                        float v = (acc[i][j][r] - mean_[i][r]) * inv_[i][r] * gv[j] + btv[j];
                        Cs[row * 264 + col] = (short)f2bf_u16(v);
                    }
                }
            __syncthreads();
            #pragma unroll
            for (int it = 0; it < 8; ++it) {
                int ci = it * 256 + t;
                int row = ci >> 5, ck = ci & 31;
                int gm = m0 + row;
                if (gm < M) {
                    uint4 v = *(const uint4*)(&Cs[row * 264 + ck * 8]);
                    *(uint4*)(&Ch[(size_t)gm * 256 + ck * 8]) = v;
                }
            }
        } else {
            #pragma unroll
            for (int i = 0; i < 4; ++i)
                #pragma unroll
                for (int r = 0; r < 4; ++r) {
                    int rowg = m0 + i * 16 + quad * 4 + r;
                    if (rowg < M) {
                        #pragma unroll
                        for (int j = 0; j < 4; ++j) {
                            int col = wn + j * 16 + l16;
                            float v = (acc[i][j][r] - mean_[i][r]) * inv_[i][r] * gv[j] + btv[j];
                            Cf[(size_t)rowg * 256 + col] = v;
                        }
                    }
                }
        }
    }
}

// ---------------------------------------------------------------------------
// fp32 -> bf16 (4 elems/thread)
// ---------------------------------------------------------------------------
__global__ void conv_bf16_kernel(const float* __restrict__ in,
                                 __hip_bfloat16* __restrict__ out, int n4)
{
    int i = blockIdx.x * 256 + threadIdx.x;
    if (i < n4) {
        float4 v = ((const float4*)in)[i];
        float f[4] = {v.x, v.y, v.z, v.w};
        uint2 o = make_uint2(pk2(f[0], f[1]), pk2(f[2], f[3]));
        ((uint2*)out)[i] = o;
    }
}

// ---------------------------------------------------------------------------
// Weight prep: W[K][N] fp32 -> WT[N][K] bf16, LDS-tiled 64x64
// ---------------------------------------------------------------------------
__global__ __launch_bounds__(256) void prep_w_kernel(
    const float* __restrict__ Wq, const float* __restrict__ Wk,
    const float* __restrict__ Wv, const float* __restrict__ Wo,
    const float* __restrict__ f1, const float* __restrict__ f2,
    unsigned short* __restrict__ WqkvT, unsigned short* __restrict__ WoT,
    unsigned short* __restrict__ f1T, unsigned short* __restrict__ f2T)
{
    __shared__ unsigned short Ts[64 * 72];
    int b = blockIdx.x, t = threadIdx.x;
    const float* S; unsigned short* D; int K, N, tile;
    if (b < 64) {
        int m = b >> 4; tile = b & 15; K = 256; N = 256;
        S = (m == 0) ? Wq : (m == 1) ? Wk : (m == 2) ? Wv : Wo;
        D = (m == 3) ? WoT : WqkvT + m * 65536;
    } else if (b < 96) { tile = b - 64; S = f1; D = f1T; K = 256; N = 512; }
    else               { tile = b - 96; S = f2; D = f2T; K = 512; N = 256; }
    int tilesN = N >> 6;
    int k0 = (tile / tilesN) << 6, n0 = (tile % tilesN) << 6;
    #pragma unroll
    for (int it = 0; it < 16; ++it) {
        int idx = it * 256 + t;
        int r = idx >> 6, c = idx & 63;
        Ts[r * 72 + c] = f2bf_u16(S[(size_t)(k0 + r) * N + n0 + c]);
    }
    __syncthreads();
    #pragma unroll
    for (int it = 0; it < 16; ++it) {
        int idx = it * 256 + t;
        int r = idx >> 6, c = idx & 63;
        D[(size_t)(n0 + r) * K + k0 + c] = Ts[c * 72 + r];
    }
}

// ---------------------------------------------------------------------------
// CSR build
// ---------------------------------------------------------------------------
__global__ void hist_kernel(const int* __restrict__ dst, int* __restrict__ counts, int E)
{
    int e = blockIdx.x * blockDim.x + threadIdx.x;
    if (e < E) atomicAdd(&counts[dst[e]], 1);
}

__global__ void scan1_kernel(const int* __restrict__ counts, int* __restrict__ starts,
                             int* __restrict__ bsums, int N)
{
    __shared__ int tmp[256];
    int t = threadIdx.x;
    int i = blockIdx.x * 256 + t;
    int v = (i < N) ? counts[i] : 0;
    tmp[t] = v;
    __syncthreads();
    for (int off = 1; off < 256; off <<= 1) {
        int add = (t >= off) ? tmp[t - off] : 0;
        __syncthreads();
        tmp[t] += add;
        __syncthreads();
    }
    if (i < N) starts[i] = tmp[t] - v;
    if (t == 255) bsums[blockIdx.x] = tmp[255];
}

__global__ void scan2_kernel(const int* __restrict__ bsums, int* __restrict__ bexc, int NB)
{
    __shared__ int tmp[256];
    int t = threadIdx.x;
    int v = (t < NB) ? bsums[t] : 0;
    tmp[t] = v;
    __syncthreads();
    for (int off = 1; off < 256; off <<= 1) {
        int add = (t >= off) ? tmp[t - off] : 0;
        __syncthreads();
        tmp[t] += add;
        __syncthreads();
    }
    bexc[t] = tmp[t] - v;
}

__global__ void scan3_kernel(int* __restrict__ starts, const int* __restrict__ bexc,
                             const int* __restrict__ counts, int* __restrict__ cursor, int N)
{
    int t = threadIdx.x;
    int i = blockIdx.x * 256 + t;
    if (i < N) {
        int val = starts[i] + bexc[blockIdx.x];
        starts[i] = val;
        cursor[i] = val;
        if (i == N - 1) starts[N] = val + counts[i];
    }
}

__global__ void scatter_kernel(const int* __restrict__ src, const int* __restrict__ dst,
                               int* __restrict__ cursor, int* __restrict__ csr_src, int E)
{
    int e = blockIdx.x * blockDim.x + threadIdx.x;
    if (e < E) {
        int d = dst[e];
        int slot = atomicAdd(&cursor[d], 1);
        csr_src[slot] = src[e];
    }
}

// ---------------------------------------------------------------------------
// Attention, bf16 QKV packed [M][768]. One wave/node; lane = (edge-slot, 8ch).
// One uint4 load serves 2 edges (16B/lane). No max-subtract (scores bounded;
// shift cancels exactly). 2 pair-slots in flight (4 edges/iter).
// R0 configuration: 40 VGPR / ~17 waves/CU. R1-R3 showed waves x depth is
// invariant (~70 in-flight gathers/CU -> 112us); walled at ~3.7 TB/s
// scattered-gather service rate (386MB FETCH on 76.8MB K/V working set).
// ---------------------------------------------------------------------------
__global__ __launch_bounds__(256) void attn_kernel(
    const __hip_bfloat16* __restrict__ QKV,
    const int* __restrict__ starts, const int* __restrict__ csr_src,
    __hip_bfloat16* __restrict__ out)   // [M][256]
{
    const int n = blockIdx.x * 4 + (threadIdx.x >> 6);
    const int lane = threadIdx.x & 63;
    const int half = lane >> 5;          // which edge of the pair
    const int c = (lane & 31) << 3;      // 8-channel base
    const size_t qb = (size_t)n * 768;
    uint4 qv = *(const uint4*)(QKV + qb + c);
    float q[8]; unpack8(qv, q);
    const int beg = starts[n], end = starts[n + 1];
    const float SC = 0.17677669529663688f;   // 32^-0.5

    float l0 = 0.f, l1 = 0.f;
    float a0[8] = {0,0,0,0,0,0,0,0};
    float a1[8] = {0,0,0,0,0,0,0,0};
    for (int e = beg; e < end; e += 4) {
        int e0 = e + half, e1 = e + 2 + half;
        int s0 = csr_src[min(e0, end - 1)];
        int s1 = csr_src[min(e1, end - 1)];
        float m0 = (e0 < end) ? 1.f : 0.f;
        float m1 = (e1 < end) ? 1.f : 0.f;
        const __hip_bfloat16* p0 = QKV + (size_t)s0 * 768 + 256 + c;
        const __hip_bfloat16* p1 = QKV + (size_t)s1 * 768 + 256 + c;
        uint4 k0 = *(const uint4*)p0;
        uint4 k1 = *(const uint4*)p1;
        uint4 v0 = *(const uint4*)(p0 + 256);
        uint4 v1 = *(const uint4*)(p1 + 256);
        float kk[8], vv[8];
        unpack8(k0, kk);
        float d0 = q[0]*kk[0] + q[1]*kk[1] + q[2]*kk[2] + q[3]*kk[3]
                 + q[4]*kk[4] + q[5]*kk[5] + q[6]*kk[6] + q[7]*kk[7];
        unpack8(k1, kk);
        float d1 = q[0]*kk[0] + q[1]*kk[1] + q[2]*kk[2] + q[3]*kk[3]
                 + q[4]*kk[4] + q[5]*kk[5] + q[6]*kk[6] + q[7]*kk[7];
        d0 += __shfl_xor(d0, 1); d0 += __shfl_xor(d0, 2);
        d1 += __shfl_xor(d1, 1); d1 += __shfl_xor(d1, 2);
        float p0s = __expf(d0 * SC) * m0;
        float p1s = __expf(d1 * SC) * m1;
        l0 += p0s; l1 += p1s;
        unpack8(v0, vv);
        #pragma unroll
        for (int k = 0; k < 8; ++k) a0[k] += p0s * vv[k];
        unpack8(v1, vv);
        #pragma unroll
        for (int k = 0; k < 8; ++k) a1[k] += p1s * vv[k];
    }
    float l = l0 + l1;
    l += __shfl_xor(l, 32);
    float o[8];
    #pragma unroll
    for (int k = 0; k < 8; ++k) {
        float v = a0[k] + a1[k];
        v += __shfl_xor(v, 32);
        o[k] = v;
    }
    float inv = 1.f / (l + 1e-8f);
    #pragma unroll
    for (int k = 0; k < 8; ++k) o[k] *= inv;
    if (half == 0)
        *(uint4*)(out + (size_t)n * DIM + c) = pack8(o);
}

// ---------------------------------------------------------------------------
extern "C" void kernel_launch(void* const* d_in, const int* in_sizes, int n_in,
                              void* d_out, int out_size, void* d_ws, size_t ws_size,
                              hipStream_t stream)
{
    const float* x     = (const float*)d_in[0];
    const int*   edge  = (const int*)d_in[1];
    const float* Wq    = (const float*)d_in[3];
    const float* Wk    = (const float*)d_in[4];
    const float* Wv    = (const float*)d_in[5];
    const float* Wo_w  = (const float*)d_in[6];
    const float* Wo_b  = (const float*)d_in[7];
    const float* ln1_g = (const float*)d_in[8];
    const float* ln1_b = (const float*)d_in[9];
    const float* ln2_g = (const float*)d_in[10];
    const float* ln2_b = (const float*)d_in[11];
    const float* fw1   = (const float*)d_in[12];
    const float* fb1   = (const float*)d_in[13];
    const float* fw2   = (const float*)d_in[14];
    const float* fb2   = (const float*)d_in[15];
    const int* srcA = edge;
    const int* dstA = edge + NEDGES;

    char* p = (char*)d_ws;
    __hip_bfloat16* QKVh = (__hip_bfloat16*)p;  p += (size_t)NNODES * 768 * 2;
    __hip_bfloat16* AOh  = (__hip_bfloat16*)p;  p += (size_t)NNODES * DIM * 2;
    __hip_bfloat16* O1h  = (__hip_bfloat16*)p;  p += (size_t)NNODES * DIM * 2;
    __hip_bfloat16* HIDh = (__hip_bfloat16*)p;  p += (size_t)NNODES * HID_DIM * 2;
    __hip_bfloat16* xh   = (__hip_bfloat16*)p;  p += (size_t)NNODES * DIM * 2;
    unsigned short* WqkvT = (unsigned short*)p; p += (size_t)768 * 256 * 2;
    unsigned short* WoT   = (unsigned short*)p; p += (size_t)256 * 256 * 2;
    unsigned short* f1T   = (unsigned short*)p; p += (size_t)512 * 256 * 2;
    unsigned short* f2T   = (unsigned short*)p; p += (size_t)256 * 512 * 2;
    int* counts = (int*)p;  p += sizeof(int) * NNODES;
    int* starts = (int*)p;  p += sizeof(int) * (NNODES + 1);
    int* bsums  = (int*)p;  p += sizeof(int) * 256;
    int* bexc   = (int*)p;  p += sizeof(int) * 256;
    int* cursor = (int*)p;  p += sizeof(int) * NNODES;
    int* csr    = (int*)p;  p += sizeof(int) * NEDGES;

    const int NB = (NNODES + 255) / 256;
    const int mT = (NNODES + 63) / 64;        // 782 M-tiles
    dim3 blk(256);

    // conversions
    conv_bf16_kernel<<<(NNODES * DIM / 4 + 255) / 256, blk, 0, stream>>>(x, xh, NNODES * DIM / 4);
    prep_w_kernel<<<128, blk, 0, stream>>>(Wq, Wk, Wv, Wo_w, fw1, fw2, WqkvT, WoT, f1T, f2T);

    // CSR by dst
    hipMemsetAsync(counts, 0, sizeof(int) * NNODES, stream);
    hist_kernel<<<(NEDGES + 255) / 256, blk, 0, stream>>>(dstA, counts, NEDGES);
    scan1_kernel<<<NB, blk, 0, stream>>>(counts, starts, bsums, NNODES);
    scan2_kernel<<<1, blk, 0, stream>>>(bsums, bexc, NB);
    scan3_kernel<<<NB, blk, 0, stream>>>(starts, bexc, counts, cursor, NNODES);
    scatter_kernel<<<(NEDGES + 255) / 256, blk, 0, stream>>>(srcA, dstA, cursor, csr, NEDGES);

    // fused QKV projection: [M,256] @ [256,768]
    gemm_bf16_kernel<0, 256><<<mT * 3, blk, 0, stream>>>(
        xh, (const __hip_bfloat16*)WqkvT, nullptr, nullptr, nullptr, nullptr,
        QKVh, nullptr, NNODES, 768);

    // segmented attention
    attn_kernel<<<NNODES / 4, blk, 0, stream>>>(QKVh, starts, csr, AOh);

    // output projection + residual(x) + LN1 -> O1h (bf16)
    gemm_bf16_kernel<2, 256><<<mT, blk, 0, stream>>>(
        AOh, (const __hip_bfloat16*)WoT, Wo_b, x, ln1_g, ln1_b,
        O1h, nullptr, NNODES, 256);

    // FFN1 + GELU -> HIDh
    gemm_bf16_kernel<1, 256><<<mT * 2, blk, 0, stream>>>(
        O1h, (const __hip_bfloat16*)f1T, fb1, nullptr, nullptr, nullptr,
        HIDh, nullptr, NNODES, 512);

    // FFN2 + residual(O1h) + LN2 -> d_out (fp32)
    gemm_bf16_kernel<3, 512><<<mT, blk, 0, stream>>>(
        HIDh, (const __hip_bfloat16*)f2T, fb2, O1h, ln2_g, ln2_b,
        nullptr, (float*)d_out, NNODES, 256);
}